// Round 1
// baseline (433.576 us; speedup 1.0000x reference)
//
#include <hip/hip_runtime.h>
#include <stdint.h>

typedef _Float16 f16;
typedef _Float16 f16x8 __attribute__((ext_vector_type(8)));
typedef _Float16 f16x4 __attribute__((ext_vector_type(4)));
typedef float f32x4 __attribute__((ext_vector_type(4)));

#define NEGF -1e30f

static __device__ __forceinline__ f32x4 mfma16(f16x8 a, f16x8 b, f32x4 c) {
    return __builtin_amdgcn_mfma_f32_16x16x32_f16(a, b, c, 0, 0, 0);
}

static __device__ __forceinline__ void gload_lds16(const void* g, void* l) {
    __builtin_amdgcn_global_load_lds(
        (const __attribute__((address_space(1))) unsigned int*)g,
        (__attribute__((address_space(3))) unsigned int*)l, 16, 0, 0);
}

// ---------------- elementwise cast f32 -> f16 ----------------
__global__ void cast_f32_f16(const float* __restrict__ src, f16* __restrict__ dst, int n) {
    int idx = blockIdx.x * blockDim.x + threadIdx.x;
    int stride = gridDim.x * blockDim.x;
    for (int i = idx * 4; i < n; i += stride * 4) {
        float4 v = *(const float4*)(src + i);
        f16x4 h;
        h[0] = (f16)v.x; h[1] = (f16)v.y; h[2] = (f16)v.z; h[3] = (f16)v.w;
        *(f16x4*)(dst + i) = h;
    }
}

// ---------------- transpose + cast: dst[c][r] = (f16)src[r][c], src is RxC ----------------
__global__ void transpose_cast(const float* __restrict__ src, f16* __restrict__ dst, int R, int C) {
    __shared__ float tile[32][33];
    const int c0 = blockIdx.x * 32, r0 = blockIdx.y * 32;
    const int tx = threadIdx.x & 31, ty = threadIdx.x >> 5;  // 32 x 8
#pragma unroll
    for (int i = 0; i < 32; i += 8)
        tile[ty + i][tx] = src[(size_t)(r0 + ty + i) * C + c0 + tx];
    __syncthreads();
#pragma unroll
    for (int i = 0; i < 32; i += 8)
        dst[(size_t)(c0 + ty + i) * R + r0 + tx] = (f16)tile[tx][ty + i];
}

// ---------------- GEMM: C = A[M][K] * Bt[N][K]^T + bias ----------------
// MODE 0: QKV projection, scatter into Q (scaled 1/8, [H][S][64]), K ([H][S][64]), Vt ([H][64][S])
// MODE 1: output projection, write f32 C
template <int MODE>
__global__ void __launch_bounds__(256, 2)
gemm_f16(const f16* __restrict__ A, const f16* __restrict__ Bt,
         const float* __restrict__ bias,
         f16* __restrict__ Qb, f16* __restrict__ Kb, f16* __restrict__ Vtb,
         float* __restrict__ Cout, int K, int N) {
    __shared__ alignas(16) f16 As[128 * 32];
    __shared__ alignas(16) f16 Bs[128 * 32];
    const int t = threadIdx.x;
    const int lane = t & 63, wid = t >> 6;
    const int wm = wid >> 1, wn = wid & 1;
    const int lr = lane & 15, lg = lane >> 4;
    const int m0 = blockIdx.y * 128, n0 = blockIdx.x * 128;
    f32x4 acc[4][4] = {};
    for (int k0 = 0; k0 < K; k0 += 32) {
#pragma unroll
        for (int i = 0; i < 2; i++) {
            const int cc = t + i * 256;
            const int rr = cc >> 2, ch = cc & 3;
            gload_lds16(A + (size_t)(m0 + rr) * K + k0 + ch * 8, (f16*)As + cc * 8);
            gload_lds16(Bt + (size_t)(n0 + rr) * K + k0 + ch * 8, (f16*)Bs + cc * 8);
        }
        __syncthreads();
        f16x8 af[4], bf[4];
#pragma unroll
        for (int i = 0; i < 4; i++)
            af[i] = *(const f16x8*)(As + (wm * 64 + i * 16 + lr) * 32 + lg * 8);
#pragma unroll
        for (int j = 0; j < 4; j++)
            bf[j] = *(const f16x8*)(Bs + (wn * 64 + j * 16 + lr) * 32 + lg * 8);
#pragma unroll
        for (int i = 0; i < 4; i++)
#pragma unroll
            for (int j = 0; j < 4; j++)
                acc[i][j] = mfma16(af[i], bf[j], acc[i][j]);
        __syncthreads();
    }
#pragma unroll
    for (int i = 0; i < 4; i++) {
#pragma unroll
        for (int j = 0; j < 4; j++) {
            const int n_g = n0 + wn * 64 + j * 16 + lr;
            const float bv = bias[n_g];
#pragma unroll
            for (int jj = 0; jj < 4; jj++) {
                const int m_g = m0 + wm * 64 + i * 16 + lg * 4 + jj;
                const float val = acc[i][j][jj] + bv;
                if (MODE == 0) {
                    if (n_g < 768) {
                        Qb[(((n_g >> 6) * 4096) + m_g) * 64 + (n_g & 63)] = (f16)(val * 0.125f);
                    } else if (n_g < 1536) {
                        const int n2 = n_g - 768;
                        Kb[(((n2 >> 6) * 4096) + m_g) * 64 + (n2 & 63)] = (f16)val;
                    } else {
                        const int n2 = n_g - 1536;
                        Vtb[((n2 >> 6) * 64 + (n2 & 63)) * 4096 + m_g] = (f16)val;
                    }
                } else {
                    Cout[(size_t)m_g * N + n_g] = val;
                }
            }
        }
    }
}

// ---------------- flash attention with rel_bias + causal ----------------
// grid: (16 q-blocks of 256 rows, 12 heads); block: 256 thr = 4 waves, each wave owns 64 q rows.
// Swapped QK: St[k][q] = K_tile @ Q^T  so softmax rows (fixed q) are lane-local per column group.
__global__ void __launch_bounds__(256, 2)
attn_fwd(const f16* __restrict__ Qb, const f16* __restrict__ Kb,
         const f16* __restrict__ Vtb, const float* __restrict__ rel_bias,
         f16* __restrict__ Ob) {
    __shared__ alignas(16) f16 Ks[64 * 64];
    __shared__ alignas(16) f16 Vs[64 * 64];
    __shared__ alignas(16) f16 Ps[4][64 * 72];
    __shared__ alignas(16) float fac[4][64];
    const int h = blockIdx.y;
    const int q0 = blockIdx.x * 256;
    const int t = threadIdx.x, lane = t & 63, wid = t >> 6;
    const int lr = lane & 15, lg = lane >> 4;
    const int q0w = q0 + wid * 64;
    const f16* Qh = Qb + (size_t)h * 4096 * 64;
    const f16* Kh = Kb + (size_t)h * 4096 * 64;
    const f16* Vh = Vtb + (size_t)h * 64 * 4096;
    const float* rbh = rel_bias + (size_t)h * 4096 * 4096;

    // Q fragments (B-operand: col = q = lr + nf*16, k = kd*32 + lg*8 + j), kept in regs
    f16x8 qf[4][2];
#pragma unroll
    for (int nf = 0; nf < 4; nf++)
#pragma unroll
        for (int kd = 0; kd < 2; kd++)
            qf[nf][kd] = *(const f16x8*)(Qh + (size_t)(q0w + nf * 16 + lr) * 64 + kd * 32 + lg * 8);

    f32x4 o[4][4] = {};
    float mrow[4] = {NEGF, NEGF, NEGF, NEGF};
    float lrow[4] = {0.f, 0.f, 0.f, 0.f};

    const int nt = (q0 >> 6) + 4;
    const int qmaxw = q0w + 63;
    for (int kt = 0; kt < nt; kt++) {
        const int kbase = kt * 64;
#pragma unroll
        for (int i = 0; i < 2; i++) {
            const int cc = t + i * 256;
            const int row = cc >> 3, off = (cc & 7) * 8;
            gload_lds16(Kh + (size_t)(kbase + row) * 64 + off, (f16*)Ks + cc * 8);
            gload_lds16(Vh + (size_t)row * 4096 + kbase + off, (f16*)Vs + cc * 8);
        }
        __syncthreads();
        if (kbase <= qmaxw) {
            // St[mf][nf]: row k = kbase + mf*16 + lg*4 + jj, col q = q0w + nf*16 + lr
            f32x4 st[4][4] = {};
#pragma unroll
            for (int kd = 0; kd < 2; kd++) {
#pragma unroll
                for (int mf = 0; mf < 4; mf++) {
                    const f16x8 kf = *(const f16x8*)(Ks + (mf * 16 + lr) * 64 + kd * 32 + lg * 8);
#pragma unroll
                    for (int nf = 0; nf < 4; nf++)
                        st[mf][nf] = mfma16(kf, qf[nf][kd], st[mf][nf]);
                }
            }
            // bias + causal + online softmax (per q, lane-local + 2 shuffles)
#pragma unroll
            for (int nf = 0; nf < 4; nf++) {
                const int q_g = q0w + nf * 16 + lr;
                float mx = NEGF;
#pragma unroll
                for (int mf = 0; mf < 4; mf++) {
                    const float4 rb = *(const float4*)(rbh + (size_t)q_g * 4096 + kbase + mf * 16 + lg * 4);
                    const float rbv[4] = {rb.x, rb.y, rb.z, rb.w};
#pragma unroll
                    for (int jj = 0; jj < 4; jj++) {
                        const int k_g = kbase + mf * 16 + lg * 4 + jj;
                        float v = st[mf][nf][jj] + rbv[jj];
                        v = (k_g > q_g) ? NEGF : v;
                        st[mf][nf][jj] = v;
                        mx = fmaxf(mx, v);
                    }
                }
                mx = fmaxf(mx, __shfl_xor(mx, 16));
                mx = fmaxf(mx, __shfl_xor(mx, 32));
                const float mnew = fmaxf(mrow[nf], mx);
                const float fscale = __expf(mrow[nf] - mnew);
                mrow[nf] = mnew;
                float rsum = 0.f;
#pragma unroll
                for (int mf = 0; mf < 4; mf++) {
                    f16x4 pv;
#pragma unroll
                    for (int jj = 0; jj < 4; jj++) {
                        const float p = __expf(st[mf][nf][jj] - mnew);
                        rsum += p;
                        pv[jj] = (f16)p;
                    }
                    *(f16x4*)(&Ps[wid][(nf * 16 + lr) * 72 + mf * 16 + lg * 4]) = pv;
                }
                rsum += __shfl_xor(rsum, 16);
                rsum += __shfl_xor(rsum, 32);
                lrow[nf] = lrow[nf] * fscale + rsum;
                if (lane < 16) fac[wid][nf * 16 + lr] = fscale;
            }
            asm volatile("s_waitcnt lgkmcnt(0)" ::: "memory");
            // rescale O accumulator rows by fscale
#pragma unroll
            for (int mf2 = 0; mf2 < 4; mf2++) {
                const float4 fv = *(const float4*)&fac[wid][mf2 * 16 + lg * 4];
                const float fvv[4] = {fv.x, fv.y, fv.z, fv.w};
#pragma unroll
                for (int nf2 = 0; nf2 < 4; nf2++)
#pragma unroll
                    for (int jj = 0; jj < 4; jj++)
                        o[mf2][nf2][jj] *= fvv[jj];
            }
            // O += P @ V  (A = P[q][k] from LDS, Bt = Vt[d][k] from LDS)
#pragma unroll
            for (int kk = 0; kk < 2; kk++) {
                f16x8 pa[4], vb[4];
#pragma unroll
                for (int mf2 = 0; mf2 < 4; mf2++)
                    pa[mf2] = *(const f16x8*)(&Ps[wid][(mf2 * 16 + lr) * 72 + kk * 32 + lg * 8]);
#pragma unroll
                for (int nf2 = 0; nf2 < 4; nf2++)
                    vb[nf2] = *(const f16x8*)(Vs + (nf2 * 16 + lr) * 64 + kk * 32 + lg * 8);
#pragma unroll
                for (int mf2 = 0; mf2 < 4; mf2++)
#pragma unroll
                    for (int nf2 = 0; nf2 < 4; nf2++)
                        o[mf2][nf2] = mfma16(pa[mf2], vb[nf2], o[mf2][nf2]);
            }
        }
        __syncthreads();
    }
    // normalize by 1/l and write O
    if (lane < 16) {
#pragma unroll
        for (int nf = 0; nf < 4; nf++) fac[wid][nf * 16 + lr] = 1.0f / lrow[nf];
    }
    asm volatile("s_waitcnt lgkmcnt(0)" ::: "memory");
#pragma unroll
    for (int mf2 = 0; mf2 < 4; mf2++) {
        const float4 fv = *(const float4*)&fac[wid][mf2 * 16 + lg * 4];
        const float fvv[4] = {fv.x, fv.y, fv.z, fv.w};
#pragma unroll
        for (int nf2 = 0; nf2 < 4; nf2++) {
#pragma unroll
            for (int jj = 0; jj < 4; jj++) {
                const int q_g = q0w + mf2 * 16 + lg * 4 + jj;
                const int dg = h * 64 + nf2 * 16 + lr;
                Ob[(size_t)q_g * 768 + dg] = (f16)(o[mf2][nf2][jj] * fvv[jj]);
            }
        }
    }
}

extern "C" void kernel_launch(void* const* d_in, const int* in_sizes, int n_in,
                              void* d_out, int out_size, void* d_ws, size_t ws_size,
                              hipStream_t stream) {
    const float* x = (const float*)d_in[0];
    const float* Wqkv = (const float*)d_in[1];
    const float* bqkv = (const float*)d_in[2];
    const float* Wout = (const float*)d_in[3];
    const float* bout = (const float*)d_in[4];
    const float* rel_bias = (const float*)d_in[5];
    // d_in[6] (causal_mask) synthesized analytically in-kernel
    float* out = (float*)d_out;

    f16* p = (f16*)d_ws;
    f16* xb = p;     p += (size_t)4096 * 768;
    f16* WqkvT = p;  p += (size_t)2304 * 768;
    f16* WoutT = p;  p += (size_t)768 * 768;
    f16* Qb = p;     p += (size_t)12 * 4096 * 64;
    f16* Kb = p;     p += (size_t)12 * 4096 * 64;
    f16* Vtb = p;    p += (size_t)12 * 4096 * 64;
    f16* Ob = p;     p += (size_t)4096 * 768;

    cast_f32_f16<<<3072, 256, 0, stream>>>(x, xb, 4096 * 768);
    transpose_cast<<<dim3(2304 / 32, 768 / 32), 256, 0, stream>>>(Wqkv, WqkvT, 768, 2304);
    transpose_cast<<<dim3(768 / 32, 768 / 32), 256, 0, stream>>>(Wout, WoutT, 768, 768);
    gemm_f16<0><<<dim3(18, 32), 256, 0, stream>>>(xb, WqkvT, bqkv, Qb, Kb, Vtb, nullptr, 768, 2304);
    attn_fwd<<<dim3(16, 12), 256, 0, stream>>>(Qb, Kb, Vtb, rel_bias, Ob);
    gemm_f16<1><<<dim3(6, 32), 256, 0, stream>>>(Ob, WoutT, bout, nullptr, nullptr, nullptr, out, 768, 768);
}

// Round 2
// 235.434 us; speedup vs baseline: 1.8416x; 1.8416x over previous
//
#include <hip/hip_runtime.h>
#include <stdint.h>

typedef _Float16 f16;
typedef _Float16 f16x8 __attribute__((ext_vector_type(8)));
typedef _Float16 f16x4 __attribute__((ext_vector_type(4)));
typedef float f32x4 __attribute__((ext_vector_type(4)));

#define NEGF -1e30f

static __device__ __forceinline__ f32x4 mfma16(f16x8 a, f16x8 b, f32x4 c) {
    return __builtin_amdgcn_mfma_f32_16x16x32_f16(a, b, c, 0, 0, 0);
}

static __device__ __forceinline__ void gload_lds16(const void* g, void* l) {
    __builtin_amdgcn_global_load_lds(
        (const __attribute__((address_space(1))) unsigned int*)g,
        (__attribute__((address_space(3))) unsigned int*)l, 16, 0, 0);
}

// ---------------- elementwise cast f32 -> f16 ----------------
__global__ void cast_f32_f16(const float* __restrict__ src, f16* __restrict__ dst, int n) {
    int idx = blockIdx.x * blockDim.x + threadIdx.x;
    int stride = gridDim.x * blockDim.x;
    for (int i = idx * 4; i < n; i += stride * 4) {
        float4 v = *(const float4*)(src + i);
        f16x4 h;
        h[0] = (f16)v.x; h[1] = (f16)v.y; h[2] = (f16)v.z; h[3] = (f16)v.w;
        *(f16x4*)(dst + i) = h;
    }
}

// ---------------- transpose + cast: dst[c][r] = (f16)src[r][c], src is RxC ----------------
__global__ void transpose_cast(const float* __restrict__ src, f16* __restrict__ dst, int R, int C) {
    __shared__ float tile[32][33];
    const int c0 = blockIdx.x * 32, r0 = blockIdx.y * 32;
    const int tx = threadIdx.x & 31, ty = threadIdx.x >> 5;  // 32 x 8
#pragma unroll
    for (int i = 0; i < 32; i += 8)
        tile[ty + i][tx] = src[(size_t)(r0 + ty + i) * C + c0 + tx];
    __syncthreads();
#pragma unroll
    for (int i = 0; i < 32; i += 8)
        dst[(size_t)(c0 + ty + i) * R + r0 + tx] = (f16)tile[tx][ty + i];
}

// ---------------- GEMM: C = A[M][K] * Bt[N][K]^T + bias ----------------
template <int MODE>
__global__ void __launch_bounds__(256, 2)
gemm_f16(const f16* __restrict__ A, const f16* __restrict__ Bt,
         const float* __restrict__ bias,
         f16* __restrict__ Qb, f16* __restrict__ Kb, f16* __restrict__ Vtb,
         float* __restrict__ Cout, int K, int N) {
    __shared__ alignas(16) f16 As[128 * 32];
    __shared__ alignas(16) f16 Bs[128 * 32];
    const int t = threadIdx.x;
    const int lane = t & 63, wid = t >> 6;
    const int wm = wid >> 1, wn = wid & 1;
    const int lr = lane & 15, lg = lane >> 4;
    const int m0 = blockIdx.y * 128, n0 = blockIdx.x * 128;
    f32x4 acc[4][4] = {};
    for (int k0 = 0; k0 < K; k0 += 32) {
#pragma unroll
        for (int i = 0; i < 2; i++) {
            const int cc = t + i * 256;
            const int rr = cc >> 2, ch = cc & 3;
            gload_lds16(A + (size_t)(m0 + rr) * K + k0 + ch * 8, (f16*)As + cc * 8);
            gload_lds16(Bt + (size_t)(n0 + rr) * K + k0 + ch * 8, (f16*)Bs + cc * 8);
        }
        __syncthreads();
        f16x8 af[4], bf[4];
#pragma unroll
        for (int i = 0; i < 4; i++)
            af[i] = *(const f16x8*)(As + (wm * 64 + i * 16 + lr) * 32 + lg * 8);
#pragma unroll
        for (int j = 0; j < 4; j++)
            bf[j] = *(const f16x8*)(Bs + (wn * 64 + j * 16 + lr) * 32 + lg * 8);
#pragma unroll
        for (int i = 0; i < 4; i++)
#pragma unroll
            for (int j = 0; j < 4; j++)
                acc[i][j] = mfma16(af[i], bf[j], acc[i][j]);
        __syncthreads();
    }
#pragma unroll
    for (int i = 0; i < 4; i++) {
#pragma unroll
        for (int j = 0; j < 4; j++) {
            const int n_g = n0 + wn * 64 + j * 16 + lr;
            const float bv = bias[n_g];
#pragma unroll
            for (int jj = 0; jj < 4; jj++) {
                const int m_g = m0 + wm * 64 + i * 16 + lg * 4 + jj;
                const float val = acc[i][j][jj] + bv;
                if (MODE == 0) {
                    if (n_g < 768) {
                        Qb[(((n_g >> 6) * 4096) + m_g) * 64 + (n_g & 63)] = (f16)(val * 0.125f);
                    } else if (n_g < 1536) {
                        const int n2 = n_g - 768;
                        Kb[(((n2 >> 6) * 4096) + m_g) * 64 + (n2 & 63)] = (f16)val;
                    } else {
                        const int n2 = n_g - 1536;
                        Vtb[((n2 >> 6) * 64 + (n2 & 63)) * 4096 + m_g] = (f16)val;
                    }
                } else {
                    Cout[(size_t)m_g * N + n_g] = val;
                }
            }
        }
    }
}

// ---------------- flash attention, split-KV (flash-decoding) ----------------
// Per head: 16 q-quads (4 waves x 64 rows); each quad's KV range [0, 4Q+4) tiles is split
// into chunks of 8 tiles -> per head sum(ceil((4Q+4)/8)) = 72 blocks; total 864 blocks.
// Each wave emits a partial (m, l, O[64][64] f32) per chunk; merge_norm combines.
__global__ void __launch_bounds__(256, 2)
attn_fwd(const f16* __restrict__ Qb, const f16* __restrict__ Kb,
         const f16* __restrict__ Vtb, const float* __restrict__ rel_bias,
         float* __restrict__ Opart, float* __restrict__ mpart, float* __restrict__ lpart) {
    __shared__ alignas(16) f16 Ks[64 * 64];
    __shared__ alignas(16) f16 Vs[64 * 64];
    __shared__ alignas(16) f16 Ps[4][64 * 72];
    __shared__ alignas(16) float fac[4][64];
    const int bid = blockIdx.x;
    const int h = bid / 72;
    int rr = bid % 72;
    int Q = 0;
    for (;;) { const int n = (Q + 2) >> 1; if (rr < n) break; rr -= n; ++Q; }
    const int c = rr;
    const int lo = c * 8;
    const int hi = min(lo + 8, 4 * Q + 4);

    const int t = threadIdx.x, lane = t & 63, wid = t >> 6;
    const int lr = lane & 15, lg = lane >> 4;
    const int g = 4 * Q + wid;       // this wave's 64-row group
    const int q0w = g * 64;
    const f16* Qh = Qb + (size_t)h * 4096 * 64;
    const f16* Kh = Kb + (size_t)h * 4096 * 64;
    const f16* Vh = Vtb + (size_t)h * 64 * 4096;
    const float* rbh = rel_bias + (size_t)h * 4096 * 4096;

    // Q fragments (B-operand: col q = lr + nf*16, k = kd*32 + lg*8 + j)
    f16x8 qf[4][2];
#pragma unroll
    for (int nf = 0; nf < 4; nf++)
#pragma unroll
        for (int kd = 0; kd < 2; kd++)
            qf[nf][kd] = *(const f16x8*)(Qh + (size_t)(q0w + nf * 16 + lr) * 64 + kd * 32 + lg * 8);

    f32x4 o[4][4] = {};
    float mrow[4] = {NEGF, NEGF, NEGF, NEGF};
    float lrow[4] = {0.f, 0.f, 0.f, 0.f};
    const int qmaxw = q0w + 63;

    for (int kt = lo; kt < hi; kt++) {
        const int kbase = kt * 64;
#pragma unroll
        for (int i = 0; i < 2; i++) {
            const int cc = t + i * 256;
            const int row = cc >> 3, off = (cc & 7) * 8;
            gload_lds16(Kh + (size_t)(kbase + row) * 64 + off, (f16*)Ks + cc * 8);
            gload_lds16(Vh + (size_t)row * 4096 + kbase + off, (f16*)Vs + cc * 8);
        }
        __syncthreads();
        if (kbase <= qmaxw) {
            // St[mf][nf]: row k = kbase + mf*16 + lg*4 + jj, col q = q0w + nf*16 + lr
            f32x4 st[4][4] = {};
#pragma unroll
            for (int kd = 0; kd < 2; kd++) {
#pragma unroll
                for (int mf = 0; mf < 4; mf++) {
                    const f16x8 kf = *(const f16x8*)(Ks + (mf * 16 + lr) * 64 + kd * 32 + lg * 8);
#pragma unroll
                    for (int nf = 0; nf < 4; nf++)
                        st[mf][nf] = mfma16(kf, qf[nf][kd], st[mf][nf]);
                }
            }
            // bias + causal + online softmax (per q, lane-local + 2 shuffles)
#pragma unroll
            for (int nf = 0; nf < 4; nf++) {
                const int q_g = q0w + nf * 16 + lr;
                const float* rbrow = rbh + (size_t)q_g * 4096 + kbase;
                float mx = NEGF;
#pragma unroll
                for (int mf = 0; mf < 4; mf++) {
                    const float4 rb = *(const float4*)(rbrow + mf * 16 + lg * 4);
                    const float rbv[4] = {rb.x, rb.y, rb.z, rb.w};
#pragma unroll
                    for (int jj = 0; jj < 4; jj++) {
                        const int k_g = kbase + mf * 16 + lg * 4 + jj;
                        float v = st[mf][nf][jj] + rbv[jj];
                        v = (k_g > q_g) ? NEGF : v;
                        st[mf][nf][jj] = v;
                        mx = fmaxf(mx, v);
                    }
                }
                mx = fmaxf(mx, __shfl_xor(mx, 16));
                mx = fmaxf(mx, __shfl_xor(mx, 32));
                const float mnew = fmaxf(mrow[nf], mx);
                const float fscale = __expf(mrow[nf] - mnew);
                mrow[nf] = mnew;
                float rsum = 0.f;
#pragma unroll
                for (int mf = 0; mf < 4; mf++) {
                    f16x4 pv;
#pragma unroll
                    for (int jj = 0; jj < 4; jj++) {
                        const float p = __expf(st[mf][nf][jj] - mnew);
                        rsum += p;
                        pv[jj] = (f16)p;
                    }
                    *(f16x4*)(&Ps[wid][(nf * 16 + lr) * 72 + mf * 16 + lg * 4]) = pv;
                }
                rsum += __shfl_xor(rsum, 16);
                rsum += __shfl_xor(rsum, 32);
                lrow[nf] = lrow[nf] * fscale + rsum;
                if (lane < 16) fac[wid][nf * 16 + lr] = fscale;
            }
            asm volatile("s_waitcnt lgkmcnt(0)" ::: "memory");
            // rescale O accumulator rows by fscale
#pragma unroll
            for (int mf2 = 0; mf2 < 4; mf2++) {
                const float4 fv = *(const float4*)&fac[wid][mf2 * 16 + lg * 4];
                const float fvv[4] = {fv.x, fv.y, fv.z, fv.w};
#pragma unroll
                for (int nf2 = 0; nf2 < 4; nf2++)
#pragma unroll
                    for (int jj = 0; jj < 4; jj++)
                        o[mf2][nf2][jj] *= fvv[jj];
            }
            // O += P @ V  (A = P[q][k] from LDS, Bt = Vt[d][k] from LDS)
#pragma unroll
            for (int kk = 0; kk < 2; kk++) {
                f16x8 pa[4], vb[4];
#pragma unroll
                for (int mf2 = 0; mf2 < 4; mf2++)
                    pa[mf2] = *(const f16x8*)(&Ps[wid][(mf2 * 16 + lr) * 72 + kk * 32 + lg * 8]);
#pragma unroll
                for (int nf2 = 0; nf2 < 4; nf2++)
                    vb[nf2] = *(const f16x8*)(Vs + (nf2 * 16 + lr) * 64 + kk * 32 + lg * 8);
#pragma unroll
                for (int mf2 = 0; mf2 < 4; mf2++)
#pragma unroll
                    for (int nf2 = 0; nf2 < 4; nf2++)
                        o[mf2][nf2] = mfma16(pa[mf2], vb[nf2], o[mf2][nf2]);
            }
        }
        __syncthreads();
    }

    // write partial (m, l, O) for this (h, g, chunk c)
    const int s = (h * 64 + g) * 8 + c;
    float* Op = Opart + (size_t)s * 4096;
#pragma unroll
    for (int mf2 = 0; mf2 < 4; mf2++)
#pragma unroll
        for (int nf2 = 0; nf2 < 4; nf2++)
#pragma unroll
            for (int jj = 0; jj < 4; jj++)
                Op[(mf2 * 16 + lg * 4 + jj) * 64 + nf2 * 16 + lr] = o[mf2][nf2][jj];
    if (lg == 0) {
#pragma unroll
        for (int nf = 0; nf < 4; nf++) {
            mpart[(size_t)s * 64 + nf * 16 + lr] = mrow[nf];
            lpart[(size_t)s * 64 + nf * 16 + lr] = lrow[nf];
        }
    }
}

// ---------------- merge partials + normalize -> Ob f16 [4096][768] ----------------
__global__ void __launch_bounds__(256)
merge_norm(const float* __restrict__ Opart, const float* __restrict__ mpart,
           const float* __restrict__ lpart, f16* __restrict__ Ob) {
    const int g = blockIdx.x, h = blockIdx.y;
    const int nc = ((g >> 2) + 2) >> 1;  // chunks valid for this group's quad
    const int t = threadIdx.x;
    const int row = t >> 2, cq = t & 3;
    const size_t base = (size_t)((h * 64 + g) * 8);
    float M = NEGF;
#pragma unroll
    for (int i = 0; i < 8; i++)
        if (i < nc) M = fmaxf(M, mpart[(base + i) * 64 + row]);
    float L = 0.f;
    float acc0[8] = {}, acc1[8] = {};
#pragma unroll
    for (int i = 0; i < 8; i++) {
        if (i < nc) {
            const float w = __expf(mpart[(base + i) * 64 + row] - M);
            L += w * lpart[(base + i) * 64 + row];
            const float4* Or = (const float4*)(Opart + (base + i) * 4096 + row * 64 + cq * 16);
            const float4 v0 = Or[0], v1 = Or[1], v2 = Or[2], v3 = Or[3];
            acc0[0] += w * v0.x; acc0[1] += w * v0.y; acc0[2] += w * v0.z; acc0[3] += w * v0.w;
            acc0[4] += w * v1.x; acc0[5] += w * v1.y; acc0[6] += w * v1.z; acc0[7] += w * v1.w;
            acc1[0] += w * v2.x; acc1[1] += w * v2.y; acc1[2] += w * v2.z; acc1[3] += w * v2.w;
            acc1[4] += w * v3.x; acc1[5] += w * v3.y; acc1[6] += w * v3.z; acc1[7] += w * v3.w;
        }
    }
    const float inv = 1.f / L;
    const int q = g * 64 + row;
    f16x8 o0, o1;
#pragma unroll
    for (int j = 0; j < 8; j++) { o0[j] = (f16)(acc0[j] * inv); o1[j] = (f16)(acc1[j] * inv); }
    *(f16x8*)(Ob + (size_t)q * 768 + h * 64 + cq * 16) = o0;
    *(f16x8*)(Ob + (size_t)q * 768 + h * 64 + cq * 16 + 8) = o1;
}

extern "C" void kernel_launch(void* const* d_in, const int* in_sizes, int n_in,
                              void* d_out, int out_size, void* d_ws, size_t ws_size,
                              hipStream_t stream) {
    const float* x = (const float*)d_in[0];
    const float* Wqkv = (const float*)d_in[1];
    const float* bqkv = (const float*)d_in[2];
    const float* Wout = (const float*)d_in[3];
    const float* bout = (const float*)d_in[4];
    const float* rel_bias = (const float*)d_in[5];
    // d_in[6] (causal_mask) synthesized analytically in-kernel
    float* out = (float*)d_out;

    f16* p = (f16*)d_ws;
    f16* xb = p;     p += (size_t)4096 * 768;
    f16* WqkvT = p;  p += (size_t)2304 * 768;
    f16* WoutT = p;  p += (size_t)768 * 768;
    f16* Qb = p;     p += (size_t)12 * 4096 * 64;
    f16* Kb = p;     p += (size_t)12 * 4096 * 64;
    f16* Vtb = p;    p += (size_t)12 * 4096 * 64;
    f16* Ob = p;     p += (size_t)4096 * 768;
    // f32 partial buffers (16B-aligned since all preceding sizes are even)
    float* fp = (float*)p;
    float* Opart = fp;  fp += (size_t)6144 * 4096;  // 100.7 MB
    float* mpart = fp;  fp += (size_t)6144 * 64;
    float* lpart = fp;  fp += (size_t)6144 * 64;

    cast_f32_f16<<<3072, 256, 0, stream>>>(x, xb, 4096 * 768);
    transpose_cast<<<dim3(2304 / 32, 768 / 32), 256, 0, stream>>>(Wqkv, WqkvT, 768, 2304);
    transpose_cast<<<dim3(768 / 32, 768 / 32), 256, 0, stream>>>(Wout, WoutT, 768, 768);
    gemm_f16<0><<<dim3(18, 32), 256, 0, stream>>>(xb, WqkvT, bqkv, Qb, Kb, Vtb, nullptr, 768, 2304);
    attn_fwd<<<dim3(864), 256, 0, stream>>>(Qb, Kb, Vtb, rel_bias, Opart, mpart, lpart);
    merge_norm<<<dim3(64, 12), 256, 0, stream>>>(Opart, mpart, lpart, Ob);
    gemm_f16<1><<<dim3(6, 32), 256, 0, stream>>>(Ob, WoutT, bout, nullptr, nullptr, nullptr, out, 768, 768);
}